// Round 1
// baseline (33787.061 us; speedup 1.0000x reference)
//
#include <hip/hip_runtime.h>
#include <math.h>

// ---------------------------------------------------------------------------
// Model constants
#define L_ENC 750
#define T_AUD 1500
#define DD    384
#define FF    1024
#define NHH   4
#define HDIM  96
#define VOCAB 60
#define T_TXT 256
#define BB    8

static __device__ __forceinline__ float sigmf(float x){ return 1.f/(1.f + __expf(-x)); }

// ---------------------------------------------------------------------------
// Generic tiled transpose: out[c*R + r] = in[r*ldin + c]   (out is [C][R])
__global__ void transpose_k(const float* __restrict__ in, int ldin, int R, int C,
                            float* __restrict__ out){
  __shared__ float t[32][33];
  int c0 = blockIdx.x*32, r0 = blockIdx.y*32;
  int x = threadIdx.x, y = threadIdx.y;
  for (int i = y; i < 32; i += 8){
    int r = r0 + i, c = c0 + x;
    t[i][x] = (r < R && c < C) ? in[(size_t)r*ldin + c] : 0.f;
  }
  __syncthreads();
  for (int i = y; i < 32; i += 8){
    int c = c0 + i, r = r0 + x;
    if (c < C && r < R) out[(size_t)c*R + r] = t[x][i];
  }
}

// K-transpose for encoder attention: KT[(b*4+h)][c][j] = QKV[b,j, 384 + h*96 + c]
__global__ void kt_k(const float* __restrict__ QKV, float* __restrict__ KT){
  __shared__ float t[32][33];
  int z = blockIdx.z; int b = z >> 2, h = z & 3;
  const float* in = QKV + (size_t)b*L_ENC*1152 + 384 + h*HDIM;
  float* out = KT + (size_t)z*HDIM*L_ENC;
  int c0 = blockIdx.x*32, r0 = blockIdx.y*32;  // rows r = j (750), cols c (96)
  int x = threadIdx.x, y = threadIdx.y;
  for (int i = y; i < 32; i += 8){
    int r = r0 + i, c = c0 + x;
    t[i][x] = (r < L_ENC && c < HDIM) ? in[(size_t)r*1152 + c] : 0.f;
  }
  __syncthreads();
  for (int i = y; i < 32; i += 8){
    int c = c0 + i, r = r0 + x;
    if (c < HDIM && r < L_ENC) out[(size_t)c*L_ENC + r] = t[x][i];
  }
}

// ---------------------------------------------------------------------------
// Generic fp32 GEMM: C[M,N] = act(A[M,K] @ W[N,K]^T + bias[N] (+ Res[M,N]))
// 128x64 tile, 256 threads, 8x4 microtile.
template<int RELU, int HASRES>
__global__ __launch_bounds__(256) void gemm_k(
    const float* __restrict__ A, int lda, const float* __restrict__ W, int ldw,
    const float* __restrict__ bias, const float* __restrict__ Res,
    float* __restrict__ C, int ldc, int M, int N, int K)
{
  __shared__ __align__(16) float As[16][132];
  __shared__ __align__(16) float Ws[16][68];
  int tid = threadIdx.x;
  int row0 = blockIdx.y*128, col0 = blockIdx.x*64;
  int tx = tid & 15, ty = tid >> 4;
  int lr = tid >> 2, lk = (tid & 3)*4;
  float acc[8][4] = {};
  for (int k0 = 0; k0 < K; k0 += 16){
    float4 a0 = make_float4(0,0,0,0), a1 = make_float4(0,0,0,0), w0 = make_float4(0,0,0,0);
    int r0i = row0 + lr, r1i = row0 + 64 + lr, wri = col0 + lr;
    if (r0i < M) a0 = *(const float4*)(A + (size_t)r0i*lda + k0 + lk);
    if (r1i < M) a1 = *(const float4*)(A + (size_t)r1i*lda + k0 + lk);
    if (wri < N) w0 = *(const float4*)(W + (size_t)wri*ldw + k0 + lk);
    As[lk+0][lr] = a0.x; As[lk+1][lr] = a0.y; As[lk+2][lr] = a0.z; As[lk+3][lr] = a0.w;
    As[lk+0][64+lr] = a1.x; As[lk+1][64+lr] = a1.y; As[lk+2][64+lr] = a1.z; As[lk+3][64+lr] = a1.w;
    Ws[lk+0][lr] = w0.x; Ws[lk+1][lr] = w0.y; Ws[lk+2][lr] = w0.z; Ws[lk+3][lr] = w0.w;
    __syncthreads();
    #pragma unroll
    for (int k = 0; k < 16; k++){
      float4 b4 = *(const float4*)&Ws[k][tx*4];
      float4 a4 = *(const float4*)&As[k][ty*8];
      float4 a5 = *(const float4*)&As[k][ty*8+4];
      acc[0][0] += a4.x*b4.x; acc[0][1] += a4.x*b4.y; acc[0][2] += a4.x*b4.z; acc[0][3] += a4.x*b4.w;
      acc[1][0] += a4.y*b4.x; acc[1][1] += a4.y*b4.y; acc[1][2] += a4.y*b4.z; acc[1][3] += a4.y*b4.w;
      acc[2][0] += a4.z*b4.x; acc[2][1] += a4.z*b4.y; acc[2][2] += a4.z*b4.z; acc[2][3] += a4.z*b4.w;
      acc[3][0] += a4.w*b4.x; acc[3][1] += a4.w*b4.y; acc[3][2] += a4.w*b4.z; acc[3][3] += a4.w*b4.w;
      acc[4][0] += a5.x*b4.x; acc[4][1] += a5.x*b4.y; acc[4][2] += a5.x*b4.z; acc[4][3] += a5.x*b4.w;
      acc[5][0] += a5.y*b4.x; acc[5][1] += a5.y*b4.y; acc[5][2] += a5.y*b4.z; acc[5][3] += a5.y*b4.w;
      acc[6][0] += a5.z*b4.x; acc[6][1] += a5.z*b4.y; acc[6][2] += a5.z*b4.z; acc[6][3] += a5.z*b4.w;
      acc[7][0] += a5.w*b4.x; acc[7][1] += a5.w*b4.y; acc[7][2] += a5.w*b4.z; acc[7][3] += a5.w*b4.w;
    }
    __syncthreads();
  }
  #pragma unroll
  for (int ii = 0; ii < 8; ii++){
    int m = row0 + ty*8 + ii;
    if (m >= M) continue;
    #pragma unroll
    for (int jj = 0; jj < 4; jj++){
      int n = col0 + tx*4 + jj;
      if (n >= N) continue;
      float v = acc[ii][jj] + bias[n];
      if (HASRES) v += Res[(size_t)m*ldc + n];
      if (RELU) v = fmaxf(v, 0.f);
      C[(size_t)m*ldc + n] = v;
    }
  }
}

// ---------------------------------------------------------------------------
// im2col for conv1 (k=3, pad=1, stride=1): P[(b*1500+t)*240 + ic*3+kt]
__global__ void im2col1(const float* __restrict__ in, float* __restrict__ P){
  int t = blockIdx.x, b = blockIdx.y, i = threadIdx.x;
  if (i >= 240) return;
  int ic = i/3, kt = i - ic*3;
  int p = t + kt - 1;
  P[((size_t)(b*T_AUD + t))*240 + i] = (p >= 0 && p < T_AUD) ? in[((size_t)(b*80 + ic))*T_AUD + p] : 0.f;
}

// im2col for conv2 (k=3, pad=1, stride=2) from X1T[(b*1500+p)*384 + ic]
__global__ __launch_bounds__(384) void im2col2(const float* __restrict__ X1T, float* __restrict__ P){
  int t = blockIdx.x, b = blockIdx.y, ic = threadIdx.x;
  size_t ob = ((size_t)(b*L_ENC + t))*1152 + (size_t)ic*3;
  #pragma unroll
  for (int kt = 0; kt < 3; kt++){
    int p = 2*t + kt - 1;
    P[ob + kt] = (p >= 0 && p < T_AUD) ? X1T[((size_t)(b*T_AUD + p))*DD + ic] : 0.f;
  }
}

// ---------------------------------------------------------------------------
// LayerNorm in-place over rows of 384
__global__ __launch_bounds__(128) void ln_k(float* __restrict__ X, const float* __restrict__ g,
                                            const float* __restrict__ bt){
  int r = blockIdx.x, tid = threadIdx.x;
  float* p = X + (size_t)r*DD;
  float v0 = p[tid], v1 = p[tid+128], v2 = p[tid+256];
  __shared__ float red[128];
  red[tid] = v0+v1+v2; __syncthreads();
  for (int k = 64; k > 0; k >>= 1){ if (tid < k) red[tid] += red[tid+k]; __syncthreads(); }
  float m = red[0] * (1.f/384.f);
  __syncthreads();
  float d0 = v0-m, d1 = v1-m, d2 = v2-m;
  red[tid] = d0*d0 + d1*d1 + d2*d2; __syncthreads();
  for (int k = 64; k > 0; k >>= 1){ if (tid < k) red[tid] += red[tid+k]; __syncthreads(); }
  float rs = rsqrtf(red[0]*(1.f/384.f) + 1e-5f);
  p[tid]     = d0*rs*g[tid]     + bt[tid];
  p[tid+128] = d1*rs*g[tid+128] + bt[tid+128];
  p[tid+256] = d2*rs*g[tid+256] + bt[tid+256];
}

// ---------------------------------------------------------------------------
// Encoder attention, fused scores+softmax+AV. 16 rows per block (wave per row).
__global__ __launch_bounds__(1024) void attn_enc(const float* __restrict__ QKV,
    const float* __restrict__ KT, float* __restrict__ ctx){
  int b = blockIdx.z, h = blockIdx.y, i0 = blockIdx.x*16;
  int tid = threadIdx.x, lane = tid & 63, wv = tid >> 6;
  __shared__ float q_s[16][96];
  __shared__ float p_s[16][752];
  __shared__ float den_s[16];
  for (int idx = tid; idx < 16*96; idx += 1024){
    int r2 = idx/96, c = idx - r2*96; int i = i0 + r2;
    q_s[r2][c] = (i < L_ENC) ? QKV[((size_t)(b*L_ENC + i))*1152 + h*HDIM + c]*0.10206207f : 0.f;
  }
  __syncthreads();
  int i = i0 + wv;
  const float* ktb = KT + ((size_t)(b*4 + h))*HDIM*L_ENC;
  if (i < L_ENC){
    float sr[12] = {0,0,0,0,0,0,0,0,0,0,0,0};
    for (int c = 0; c < 96; c++){
      float qc = q_s[wv][c];
      const float* kr = ktb + c*L_ENC + lane;
      #pragma unroll
      for (int jt = 0; jt < 12; jt++) sr[jt] += qc*kr[jt*64];
    }
    float mx = -1e30f;
    #pragma unroll
    for (int jt = 0; jt < 12; jt++){ if (lane + jt*64 < L_ENC) mx = fmaxf(mx, sr[jt]); }
    #pragma unroll
    for (int o = 32; o > 0; o >>= 1) mx = fmaxf(mx, __shfl_xor(mx, o));
    float den = 0.f;
    #pragma unroll
    for (int jt = 0; jt < 12; jt++){
      int j = lane + jt*64;
      if (j < L_ENC){ float e = __expf(sr[jt]-mx); p_s[wv][j] = e; den += e; }
    }
    #pragma unroll
    for (int o = 32; o > 0; o >>= 1) den += __shfl_xor(den, o);
    if (lane == 0) den_s[wv] = den;
  }
  __syncthreads();
  if (i < L_ENC){
    float idn = 1.f/den_s[wv];
    const float* vb = QKV + (size_t)b*L_ENC*1152 + 768 + h*HDIM;
    float a0 = 0.f, a1 = 0.f;
    for (int j = 0; j < L_ENC; j++){
      float pj = p_s[wv][j];
      const float* vr = vb + (size_t)j*1152;
      a0 += pj*vr[lane];
      if (lane < 32) a1 += pj*vr[lane + 64];
    }
    size_t ob = ((size_t)(b*L_ENC + i))*DD + h*HDIM;
    ctx[ob + lane] = a0*idn;
    if (lane < 32) ctx[ob + lane + 64] = a1*idn;
  }
}

// ---------------------------------------------------------------------------
// Decode precompute helpers
__global__ __launch_bounds__(384) void embed_k(const float* __restrict__ emb,
    const int* __restrict__ tgtA, float* __restrict__ E){
  int row = blockIdx.x; int t = row >> 3, b = row & 7;
  int tok = 0;
  if (t > 0){ int v = tgtA[b*T_TXT + t - 1]; tok = (v == -100) ? 0 : v; }
  E[(size_t)row*DD + threadIdx.x] = emb[(size_t)tok*DD + threadIdx.x];
}

__global__ __launch_bounds__(256) void vla_k(const float* __restrict__ EA,
    const float* __restrict__ lav, const float* __restrict__ lain, float* __restrict__ VLA){
  int row = blockIdx.x*4 + (threadIdx.x >> 6);
  int lane = threadIdx.x & 63;
  if (row >= BB*L_ENC) return;
  const float* p = EA + (size_t)row*DD;
  float s = 0.f;
  for (int d = lane; d < DD; d += 64) s += p[d]*lav[d];
  #pragma unroll
  for (int o = 32; o > 0; o >>= 1) s += __shfl_xor(s, o);
  if (lane == 0) VLA[row] = s + lain[2];
}

__global__ void invn_k(const float* __restrict__ inv, float* __restrict__ INVN){
  int row = blockIdx.x; int lane = threadIdx.x;
  float s = 0.f;
  for (int d = lane; d < DD; d += 64){ float v = inv[(size_t)row*DD + d]; s += v*v; }
  #pragma unroll
  for (int o = 32; o > 0; o >>= 1) s += __shfl_xor(s, o);
  if (lane == 0) INVN[row] = sqrtf(s);
}

// ---------------------------------------------------------------------------
// Decode K1/K4: GRU gate pre-activations. NR gate-rows, KH hidden size.
// GI[b][r] = GE[t][b][r] + sum_k ctx[b][k]*WIT[k][r]
// GH[b][r] = bhh[r]      + sum_k h[b][k]  *WHT[k][r]
template<int NR, int KH>
__global__ __launch_bounds__(256) void dec_gates(
    const float* __restrict__ WIT, const float* __restrict__ WHT,
    const float* __restrict__ ctxv, const float* __restrict__ hv,
    const float* __restrict__ GE, const float* __restrict__ bhh,
    float* __restrict__ GI, float* __restrict__ GH, int t)
{
  constexpr int CH = (KH + 7) / 8;
  __shared__ __align__(16) float ac[384][8];
  __shared__ __align__(16) float hh[KH][8];
  __shared__ float pgi[8][32][8];
  __shared__ float pgh[8][32][8];
  int tid = threadIdx.x;
  for (int idx = tid; idx < 384*8; idx += 256){ int b = idx/384, k = idx - b*384; ac[k][b] = ctxv[idx]; }
  for (int idx = tid; idx < KH*8;  idx += 256){ int b = idx/KH,  k = idx - b*KH;  hh[k][b] = hv[idx]; }
  __syncthreads();
  int rl = tid & 31, kp = tid >> 5;
  int r = blockIdx.x*32 + rl;
  float gi[8] = {}, gh[8] = {};
  if (r < NR){
    int k0 = kp*48;
    for (int k = k0; k < k0+48; k++){
      float w = WIT[(size_t)k*NR + r];
      const float4 a0 = *(const float4*)&ac[k][0];
      const float4 a1 = *(const float4*)&ac[k][4];
      gi[0] += a0.x*w; gi[1] += a0.y*w; gi[2] += a0.z*w; gi[3] += a0.w*w;
      gi[4] += a1.x*w; gi[5] += a1.y*w; gi[6] += a1.z*w; gi[7] += a1.w*w;
    }
    int h0 = kp*CH, h1 = (h0 + CH < KH) ? h0 + CH : KH;
    for (int k = h0; k < h1; k++){
      float w = WHT[(size_t)k*NR + r];
      const float4 a0 = *(const float4*)&hh[k][0];
      const float4 a1 = *(const float4*)&hh[k][4];
      gh[0] += a0.x*w; gh[1] += a0.y*w; gh[2] += a0.z*w; gh[3] += a0.w*w;
      gh[4] += a1.x*w; gh[5] += a1.y*w; gh[6] += a1.z*w; gh[7] += a1.w*w;
    }
  }
  #pragma unroll
  for (int b = 0; b < 8; b++){ pgi[kp][rl][b] = gi[b]; pgh[kp][rl][b] = gh[b]; }
  __syncthreads();
  if (tid < 32){
    int rr = blockIdx.x*32 + tid;
    if (rr < NR){
      #pragma unroll
      for (int b = 0; b < 8; b++){
        float s1 = 0.f, s2 = 0.f;
        #pragma unroll
        for (int kq = 0; kq < 8; kq++){ s1 += pgi[kq][tid][b]; s2 += pgh[kq][tid][b]; }
        GI[(size_t)b*NR + rr] = s1 + GE[((size_t)t*8 + b)*NR + rr];
        GH[(size_t)b*NR + rr] = s2 + bhh[rr];
      }
    }
  }
}

// ---------------------------------------------------------------------------
// Decode K2: asr GRU combine + rank-1 750x750 attention row + re-init accumulators.
__global__ __launch_bounds__(256) void dec_h_attn(
    const float* __restrict__ GI, const float* __restrict__ GH, float* __restrict__ HASR,
    const float* __restrict__ Acur, float* __restrict__ Anxt, const float* __restrict__ VLA,
    const float* __restrict__ laq, const float* __restrict__ lak, const float* __restrict__ lain,
    const float* __restrict__ laow, const float* __restrict__ laob,
    float* __restrict__ ACTX, float* __restrict__ SCTX, float* __restrict__ PREP,
    const float* __restrict__ h2ab, const float* __restrict__ d2ab)
{
  int b = blockIdx.y, tid = threadIdx.x;
  int lane = tid & 63, wv = tid >> 6;
  __shared__ float kk[750], vv[750];
  float kw = lak[0], kb = lain[1];
  for (int j = tid; j < L_ENC; j += 256){
    kk[j] = Acur[b*L_ENC + j]*kw + kb;
    vv[j] = VLA[b*L_ENC + j];
  }
  if (blockIdx.x == 0){
    for (int d = tid; d < DD; d += 256){
      ACTX[b*DD + d] = 0.f; SCTX[b*DD + d] = 0.f;
      PREP[b*DD + d] = h2ab[d] + d2ab[d];
    }
  }
  __syncthreads();
  int i = blockIdx.x*4 + wv;
  if (i >= L_ENC) return;
  int base = b*2250 + i;
  float rr = sigmf(GI[base] + GH[base]);
  float zz = sigmf(GI[base+750] + GH[base+750]);
  float nn = tanhf(GI[base+1500] + rr*GH[base+1500]);
  float h = (1.f - zz)*nn + zz*HASR[b*L_ENC + i];
  float q = h*laq[0] + lain[0];
  float sr[12]; float mx = -1e30f;
  #pragma unroll
  for (int jt = 0; jt < 12; jt++){
    int j = lane + jt*64;
    float s = (j < L_ENC) ? q*kk[j] : -1e30f;
    sr[jt] = s; mx = fmaxf(mx, s);
  }
  #pragma unroll
  for (int o = 32; o > 0; o >>= 1) mx = fmaxf(mx, __shfl_xor(mx, o));
  float se = 0.f, sv = 0.f;
  #pragma unroll
  for (int jt = 0; jt < 12; jt++){
    int j = lane + jt*64;
    if (j < L_ENC){ float e = __expf(sr[jt] - mx); se += e; sv += e*vv[j]; }
  }
  #pragma unroll
  for (int o = 32; o > 0; o >>= 1){ se += __shfl_xor(se, o); sv += __shfl_xor(sv, o); }
  if (lane == 0){
    HASR[b*L_ENC + i] = h;
    Anxt[b*L_ENC + i] = (sv/se)*laow[0] + laob[0];
  }
}

// ---------------------------------------------------------------------------
// Decode K3: contexts + h2a partial.  Accumulates into zeroed ACTX/SCTX/PREP.
__global__ __launch_bounds__(384) void dec_ctx(
    const float* __restrict__ EA, const float* __restrict__ ED, const float* __restrict__ H2AT,
    const float* __restrict__ Anxt, const float* __restrict__ HASR,
    float* __restrict__ ACTX, float* __restrict__ SCTX, float* __restrict__ PREP)
{
  int b = blockIdx.y, ls = blockIdx.x, d = threadIdx.x;
  int l0 = ls*47; int n = L_ENC - l0; if (n > 47) n = 47;
  __shared__ float wl[47], hl[47];
  for (int idx = d; idx < n; idx += 384){ wl[idx] = Anxt[b*L_ENC + l0 + idx]; hl[idx] = HASR[b*L_ENC + l0 + idx]; }
  __syncthreads();
  float a = 0.f, s = 0.f, hp = 0.f;
  for (int j = 0; j < n; j++){
    int l = l0 + j;
    a  += EA[((size_t)(b*L_ENC + l))*DD + d]*wl[j];
    s  += ED[((size_t)(b*L_ENC + l))*DD + d]*wl[j];
    hp += H2AT[(size_t)l*DD + d]*hl[j];
  }
  atomicAdd(&ACTX[b*DD + d], a);
  atomicAdd(&SCTX[b*DD + d], s);
  atomicAdd(&PREP[b*DD + d], a + hp);
}

// ---------------------------------------------------------------------------
// Decode K6: diar GRU combine, speaker softmax, spk_state, d2a matvec, logits, loss.
__global__ __launch_bounds__(384) void dec_final(
    const float* __restrict__ GID, const float* __restrict__ GHD,
    const float* __restrict__ HDc, float* __restrict__ HDn,
    const float* __restrict__ inv, const float* __restrict__ INVN,
    const float* __restrict__ PREP, const float* __restrict__ D2AT,
    const float* __restrict__ AOT, const float* __restrict__ aob,
    const int* __restrict__ tgtA, const int* __restrict__ tgtD,
    int t, float* __restrict__ out, float* __restrict__ lacc)
{
  int b = blockIdx.x, tid = threadIdx.x;
  __shared__ float hd_s[384], ss_s[384], pre_s[384], red[512], beta_s[8], sc_s[8], scp[8][48];
  int base = b*1152 + tid;
  float rr = sigmf(GID[base] + GHD[base]);
  float zz = sigmf(GID[base+384] + GHD[base+384]);
  float nn = tanhf(GID[base+768] + rr*GHD[base+768]);
  float h = (1.f - zz)*nn + zz*HDc[b*DD + tid];
  hd_s[tid] = h; HDn[b*DD + tid] = h;
  red[tid] = h*h; if (tid < 128) red[384 + tid] = 0.f;
  __syncthreads();
  for (int s = 256; s > 0; s >>= 1){ if (tid < s) red[tid] += red[tid + s]; __syncthreads(); }
  float hn = sqrtf(red[0]);
  int sg = tid/48, si = tid - sg*48;
  float ps = 0.f;
  for (int j = si; j < DD; j += 48) ps += inv[((size_t)(b*8 + sg))*DD + j]*hd_s[j];
  scp[sg][si] = ps;
  __syncthreads();
  if (tid < 8){
    float sum = 0.f;
    for (int i2 = 0; i2 < 48; i2++) sum += scp[tid][i2];
    sc_s[tid] = sum / (hn * INVN[b*8 + tid]);
  }
  __syncthreads();
  if (tid == 0){
    float mx = -1e30f;
    for (int s2 = 0; s2 < 8; s2++) mx = fmaxf(mx, sc_s[s2]);
    float sm = 0.f;
    for (int s2 = 0; s2 < 8; s2++){ float e = __expf(sc_s[s2] - mx); beta_s[s2] = e; sm += e; }
    float isv = 1.f/sm;
    for (int s2 = 0; s2 < 8; s2++) beta_s[s2] *= isv;
    int td = tgtD[b*T_TXT + t];
    if (td != -100){ atomicAdd(&lacc[2], beta_s[td]); atomicAdd(&lacc[3], 1.f); }
  }
  __syncthreads();
  if (tid < 8) out[122880 + ((size_t)(b*T_TXT + t))*8 + tid] = beta_s[tid];
  float ssv = 0.f;
  #pragma unroll
  for (int s2 = 0; s2 < 8; s2++) ssv += inv[((size_t)(b*8 + s2))*DD + tid]*beta_s[s2];
  ss_s[tid] = ssv;
  __syncthreads();
  float p = PREP[b*DD + tid];
  for (int k = 0; k < DD; k++) p += ss_s[k]*D2AT[k*60 ? k*384 + tid : k*384 + tid];
  pre_s[tid] = p;
  __syncthreads();
  if (tid < VOCAB){
    float lg = aob[tid];
    for (int d2 = 0; d2 < DD; d2++) lg += pre_s[d2]*AOT[d2*VOCAB + tid];
    out[((size_t)(b*T_TXT + t))*VOCAB + tid] = lg;
    int ta = tgtA[b*T_TXT + t];
    if (ta == tid) atomicAdd(&lacc[0], lg);
    if (tid == 0 && ta != -100) atomicAdd(&lacc[1], 1.f);
  }
}

__global__ void loss_final_k(const float* __restrict__ lacc, float* __restrict__ out){
  if (threadIdx.x == 0 && blockIdx.x == 0){
    float la = lacc[0]/fmaxf(lacc[1], 1.f);
    float ld = lacc[2]/fmaxf(lacc[3], 1.f);
    out[139264] = -(la + ld);
  }
}

// ---------------------------------------------------------------------------
extern "C" void kernel_launch(void* const* d_in, const int* in_sizes, int n_in,
                              void* d_out, int out_size, void* d_ws, size_t ws_size,
                              hipStream_t stream)
{
  (void)in_sizes; (void)n_in; (void)out_size; (void)ws_size;
  float* ws  = (float*)d_ws;
  float* out = (float*)d_out;

  const float* IN0   = (const float*)d_in[0];
  const float* SPK   = (const float*)d_in[1];
  const float* C1W   = (const float*)d_in[2];
  const float* C1B   = (const float*)d_in[3];
  const float* C2W   = (const float*)d_in[4];
  const float* C2B   = (const float*)d_in[5];
  const float* LAQ   = (const float*)d_in[30];
  const float* LAK   = (const float*)d_in[31];
  const float* LAV   = (const float*)d_in[32];
  const float* LAIB  = (const float*)d_in[33];
  const float* LAOW  = (const float*)d_in[34];
  const float* LAOB  = (const float*)d_in[35];
  const float* EMB   = (const float*)d_in[36];
  const float* AWIH  = (const float*)d_in[37];
  const float* AWHH  = (const float*)d_in[38];
  const float* ABIH  = (const float*)d_in[39];
  const float* ABHH  = (const float*)d_in[40];
  const float* DWIH  = (const float*)d_in[41];
  const float* DWHH  = (const float*)d_in[42];
  const float* DBIH  = (const float*)d_in[43];
  const float* DBHH  = (const float*)d_in[44];
  const float* AOW   = (const float*)d_in[45];
  const float* AOB   = (const float*)d_in[46];
  const float* D2AW  = (const float*)d_in[47];
  const float* D2AB  = (const float*)d_in[48];
  const float* H2AW  = (const float*)d_in[49];
  const float* H2AB  = (const float*)d_in[50];
  const int*   TGTA  = (const int*)d_in[51];
  const int*   TGTD  = (const int*)d_in[52];

  // ---- workspace layout (float offsets) ----
  const size_t O_X   = 0;
  const size_t O_EA  = 2304000;
  const size_t O_ED  = 4608000;
  const size_t O_ST  = 6912000;
  const size_t HASR  = O_ST + 0;
  const size_t ATT0  = O_ST + 6000;
  const size_t ATT1  = O_ST + 12000;
  const size_t HD0   = O_ST + 18000;
  const size_t HD1   = O_ST + 21072;
  const size_t ACTX  = O_ST + 24144;
  const size_t SCTX  = O_ST + 27216;
  const size_t PREP  = O_ST + 30288;
  const size_t GIA   = O_ST + 33360;
  const size_t GHA   = O_ST + 51360;
  const size_t GID   = O_ST + 69360;
  const size_t GHD   = O_ST + 78576;
  const size_t LACC  = O_ST + 87792;
  const size_t VLA   = O_ST + 87800;
  const size_t INVN  = O_ST + 93800;
  const size_t O_SCR = 7006000;
  const size_t S_QKV = O_SCR;                 // also P2 (6,912,000)
  const size_t S_KT  = O_SCR + 6912000;       // also X1T low
  const size_t S_CTX = O_SCR + 9216000;       // also X1T high
  const size_t S_Y   = O_SCR + 11520000;
  const size_t S_H   = O_SCR + 13824000;      // also P1
  const size_t X1T   = S_KT;
  const size_t P1    = S_H;
  const size_t P2    = S_QKV;
  // decode precompute overlay (written after encoder)
  const size_t WIHAT_A = O_SCR + 0;
  const size_t WHHT_A  = O_SCR + 864000;
  const size_t WIHAT_D = O_SCR + 2551500;
  const size_t WHHT_D  = O_SCR + 2993868;
  const size_t H2AT    = O_SCR + 3436236;
  const size_t D2AT    = O_SCR + 3724236;
  const size_t AOT     = O_SCR + 3871692;
  const size_t EMBT    = O_SCR + 3894732;
  const size_t GEA     = O_SCR + 4681164;
  const size_t GED     = O_SCR + 9289164;

  // 1) zero decode state + loss accumulators
  hipMemsetAsync((void*)(ws + O_ST), 0, 94000*sizeof(float), stream);

  // 2) convs via im2col + GEMM
  im2col1<<<dim3(1500,8), 256, 0, stream>>>(IN0, ws + P1);
  gemm_k<1,0><<<dim3(6,94), 256, 0, stream>>>(ws+P1, 240, C1W, 240, C1B, nullptr, ws+X1T, 384, 12000, 384, 240);
  im2col2<<<dim3(750,8), 384, 0, stream>>>(ws+X1T, ws+P2);
  gemm_k<1,0><<<dim3(6,47), 256, 0, stream>>>(ws+P2, 1152, C2W, 1152, C2B, nullptr, ws+O_X, 384, 6000, 384, 1152);

  hipMemcpyAsync(ws+O_EA, ws+O_X, 2304000*sizeof(float), hipMemcpyDeviceToDevice, stream);
  hipMemcpyAsync(ws+O_ED, ws+O_X, 2304000*sizeof(float), hipMemcpyDeviceToDevice, stream);

  // 3) encoder stacks
  auto enc_layer = [&](float* Xb, const float* qw, const float* qb, const float* ow,
                       const float* ob, const float* f1w, const float* f1b,
                       const float* f2w, const float* f2b,
                       const float* g1, const float* b1, const float* g2, const float* b2){
    gemm_k<0,0><<<dim3(18,47), 256, 0, stream>>>(Xb, 384, qw, 384, qb, nullptr, ws+S_QKV, 1152, 6000, 1152, 384);
    kt_k<<<dim3(3,24,32), dim3(32,8), 0, stream>>>(ws+S_QKV, ws+S_KT);
    attn_enc<<<dim3(47,4,8), 1024, 0, stream>>>(ws+S_QKV, ws+S_KT, ws+S_CTX);
    gemm_k<0,1><<<dim3(6,47), 256, 0, stream>>>(ws+S_CTX, 384, ow, 384, ob, Xb, ws+S_Y, 384, 6000, 384, 384);
    ln_k<<<6000, 128, 0, stream>>>(ws+S_Y, g1, b1);
    gemm_k<1,0><<<dim3(16,47), 256, 0, stream>>>(ws+S_Y, 384, f1w, 384, f1b, nullptr, ws+S_H, 1024, 6000, 1024, 384);
    gemm_k<0,1><<<dim3(6,47), 256, 0, stream>>>(ws+S_H, 1024, f2w, 1024, f2b, ws+S_Y, Xb, 384, 6000, 384, 1024);
    ln_k<<<6000, 128, 0, stream>>>(Xb, g2, b2);
  };
  for (int st = 0; st < 2; st++){
    int base = (st == 0) ? 6 : 18;
    float* Xb = ws + ((st == 0) ? O_EA : O_ED);
    const float* qkvw = (const float*)d_in[base+0];
    const float* qkvb = (const float*)d_in[base+1];
    const float* aow  = (const float*)d_in[base+2];
    const float* aob2 = (const float*)d_in[base+3];
    const float* f1w  = (const float*)d_in[base+4];
    const float* f1b  = (const float*)d_in[base+5];
    const float* f2w  = (const float*)d_in[base+6];
    const float* f2b  = (const float*)d_in[base+7];
    const float* g1   = (const float*)d_in[base+8];
    const float* b1   = (const float*)d_in[base+9];
    const float* g2   = (const float*)d_in[base+10];
    const float* b2   = (const float*)d_in[base+11];
    for (int l = 0; l < 2; l++){
      enc_layer(Xb, qkvw + (size_t)l*1152*384, qkvb + (size_t)l*1152,
                aow + (size_t)l*384*384, aob2 + (size_t)l*384,
                f1w + (size_t)l*1024*384, f1b + (size_t)l*1024,
                f2w + (size_t)l*384*1024, f2b + (size_t)l*384,
                g1 + (size_t)l*384, b1 + (size_t)l*384, g2 + (size_t)l*384, b2 + (size_t)l*384);
    }
  }

  // 4) decode precompute (overlays encoder scratch)
  transpose_k<<<dim3(12,71), dim3(32,8), 0, stream>>>(AWIH, 768, 2250, 384, ws+WIHAT_A);
  transpose_k<<<dim3(24,71), dim3(32,8), 0, stream>>>(AWHH, 750, 2250, 750, ws+WHHT_A);
  transpose_k<<<dim3(12,36), dim3(32,8), 0, stream>>>(DWIH, 768, 1152, 384, ws+WIHAT_D);
  transpose_k<<<dim3(12,36), dim3(32,8), 0, stream>>>(DWHH, 384, 1152, 384, ws+WHHT_D);
  transpose_k<<<dim3(24,12), dim3(32,8), 0, stream>>>(H2AW, 750, 384, 750, ws+H2AT);
  transpose_k<<<dim3(12,12), dim3(32,8), 0, stream>>>(D2AW, 384, 384, 384, ws+D2AT);
  transpose_k<<<dim3(12,2),  dim3(32,8), 0, stream>>>(AOW, 384, 60, 384, ws+AOT);
  embed_k<<<2048, 384, 0, stream>>>(EMB, TGTA, ws+EMBT);
  gemm_k<0,0><<<dim3(36,16), 256, 0, stream>>>(ws+EMBT, 384, AWIH+384, 768, ABIH, nullptr, ws+GEA, 2250, 2048, 2250, 384);
  gemm_k<0,0><<<dim3(18,16), 256, 0, stream>>>(ws+EMBT, 384, DWIH+384, 768, DBIH, nullptr, ws+GED, 1152, 2048, 1152, 384);
  vla_k<<<1500, 256, 0, stream>>>(ws+O_EA, LAV, LAIB, ws+VLA);
  invn_k<<<64, 64, 0, stream>>>(SPK, ws+INVN);

  // 5) sequential decode, 5 kernels per step
  for (int t = 0; t < T_TXT; t++){
    const float* acur = ws + ((t & 1) ? ATT1 : ATT0);
    float*       anxt = ws + ((t & 1) ? ATT0 : ATT1);
    const float* hdc  = ws + ((t & 1) ? HD1 : HD0);
    float*       hdn  = ws + ((t & 1) ? HD0 : HD1);
    dec_gates<2250,750><<<dim3(71), 256, 0, stream>>>(ws+WIHAT_A, ws+WHHT_A, ws+ACTX, ws+HASR,
                                                      ws+GEA, ABHH, ws+GIA, ws+GHA, t);
    dec_h_attn<<<dim3(188,8), 256, 0, stream>>>(ws+GIA, ws+GHA, ws+HASR, acur, anxt, ws+VLA,
                                                LAQ, LAK, LAIB, LAOW, LAOB,
                                                ws+ACTX, ws+SCTX, ws+PREP, H2AB, D2AB);
    dec_ctx<<<dim3(16,8), 384, 0, stream>>>(ws+O_EA, ws+O_ED, ws+H2AT, anxt, ws+HASR,
                                            ws+ACTX, ws+SCTX, ws+PREP);
    dec_gates<1152,384><<<dim3(36), 256, 0, stream>>>(ws+WIHAT_D, ws+WHHT_D, ws+SCTX, hdc,
                                                      ws+GED, DBHH, ws+GID, ws+GHD, t);
    dec_final<<<8, 384, 0, stream>>>(ws+GID, ws+GHD, hdc, hdn, SPK, ws+INVN, ws+PREP,
                                     ws+D2AT, ws+AOT, AOB, TGTA, TGTD, t, out, ws+LACC);
  }
  loss_final_k<<<1, 64, 0, stream>>>(ws+LACC, out);
}